// Round 1
// baseline (46548.987 us; speedup 1.0000x reference)
//
#include <hip/hip_runtime.h>
#include <hip/hip_bf16.h>
#include <cstdint>
#include <cstddef>

// Seq2Seq LSTM: L=168 enc steps, T=24 dec steps, B=512, IN=64, H=1024, OUT=1.
// Each cell-step: z[512,4096] = A1@B1^T + A2@B2^T + bias  (A=[input|h_prev]),
// then i,f,g,o gates -> c_new, h_new. Sequential chain of 576 cells.
//
// Precision: fp32 inputs split on-the-fly into bf16 hi (truncate) + lo (RNE of
// remainder); 3 MFMA products (hh + hl + lh) give ~17-bit effective mantissa,
// ~1e-5 z-error/step vs 2.2e-4 output threshold.

typedef __attribute__((ext_vector_type(8))) short bf16x8;
typedef __attribute__((ext_vector_type(4))) float f32x4;

__device__ __forceinline__ void split1(float x, ushort &hi, ushort &lo) {
  unsigned u = __float_as_uint(x);
  hi = (ushort)(u >> 16);                       // truncated bf16 (exact top bits)
  float r = x - __uint_as_float(u & 0xffff0000u); // exact remainder
  unsigned v = __float_as_uint(r);
  v += 0x7fffu + ((v >> 16) & 1u);              // RNE to bf16
  lo = (ushort)(v >> 16);
}

struct SMemS {
  ushort Ah[128 * 72];  // A tile 128 x 64, +8 pad (2-way bank alias = free)
  ushort Al[128 * 72];
  ushort Bh[64 * 72];   // B tile 64 z-cols x 64
  ushort Bl[64 * 72];
};
union SMemU {
  SMemS s;
  float z[128 * 68];    // fp32 z tile for epilogue (pad 68 -> conflict-free)
};

// K1: input-operand width (64 for enc-first x, 1024 for h inputs).
template <int K1>
__global__ __launch_bounds__(256, 1) void lstm_cell(
    const float* __restrict__ A1, const float* __restrict__ A2,
    const float* __restrict__ B1, const float* __restrict__ B2,
    const float* __restrict__ bias, float* __restrict__ cst,
    float* __restrict__ hout, float scaleB1) {
  constexpr int NT = (K1 + 1024) / 64;  // 17 or 32 K-tiles of BK=64
  __shared__ SMemU sm;

  const int tid = threadIdx.x;
  // XCD swizzle: 4 M-blocks sharing one W-panel land on the same XCD/L2.
  const int bw = blockIdx.x;
  const int wid = (bw & 7) * 32 + (bw >> 3);
  const int bm0 = (wid & 3) * 128;      // batch-row block
  const int hc0 = (wid >> 2) * 16;      // h-column block (16 cols x 4 gates)

  const int frow = tid >> 4;            // staging row 0..15
  const int fcol = (tid & 15) << 2;     // staging float4 col
  const int w = tid >> 6, lane = tid & 63;
  const int wm = w >> 1, wn = w & 1;    // wave 2x2 over 128x64
  const int l15 = lane & 15, l4 = lane >> 4;

  f32x4 acc[4][2];
#pragma unroll
  for (int m = 0; m < 4; ++m)
#pragma unroll
    for (int n = 0; n < 2; ++n) acc[m][n] = (f32x4){0.f, 0.f, 0.f, 0.f};

  float4 va0[8], vb0[4], va1[8], vb1[4];

  auto stage_issue = [&](float4(&va)[8], float4(&vb)[4], int kt) {
    const int k0 = kt * 64;
    const float* sA; int ldA, ka;
    if (k0 < K1) { sA = A1; ldA = K1; ka = k0; }
    else         { sA = A2; ldA = 1024; ka = k0 - K1; }
#pragma unroll
    for (int i = 0; i < 8; ++i)
      va[i] = *(const float4*)(sA + (size_t)(bm0 + frow + 16 * i) * ldA + ka + fcol);
    const float* sB; int ldB, kb;
    if (k0 < K1) { sB = B1; ldB = K1; kb = k0; }
    else         { sB = B2; ldB = 1024; kb = k0 - K1; }
#pragma unroll
    for (int i = 0; i < 4; ++i)  // z-col c = frow + 16*i -> W row i*1024 + hc0 + frow
      vb[i] = *(const float4*)(sB + (size_t)(i * 1024 + hc0 + frow) * ldB + kb + fcol);
  };

  auto stage_write = [&](float4(&va)[8], float4(&vb)[4], float scB) {
#pragma unroll
    for (int i = 0; i < 8; ++i) {
      ushort h0, h1, h2, h3, l0, l1, l2, l3;
      split1(va[i].x, h0, l0); split1(va[i].y, h1, l1);
      split1(va[i].z, h2, l2); split1(va[i].w, h3, l3);
      *(ushort4*)&sm.s.Ah[(frow + 16 * i) * 72 + fcol] = make_ushort4(h0, h1, h2, h3);
      *(ushort4*)&sm.s.Al[(frow + 16 * i) * 72 + fcol] = make_ushort4(l0, l1, l2, l3);
    }
#pragma unroll
    for (int i = 0; i < 4; ++i) {
      ushort h0, h1, h2, h3, l0, l1, l2, l3;
      split1(vb[i].x * scB, h0, l0); split1(vb[i].y * scB, h1, l1);
      split1(vb[i].z * scB, h2, l2); split1(vb[i].w * scB, h3, l3);
      *(ushort4*)&sm.s.Bh[(frow + 16 * i) * 72 + fcol] = make_ushort4(h0, h1, h2, h3);
      *(ushort4*)&sm.s.Bl[(frow + 16 * i) * 72 + fcol] = make_ushort4(l0, l1, l2, l3);
    }
  };

  auto compute = [&]() {
#pragma unroll
    for (int s = 0; s < 2; ++s) {  // two K=32 MFMA phases per BK=64 tile
      bf16x8 ah[4], al[4], bh[2], bl[2];
#pragma unroll
      for (int m = 0; m < 4; ++m) {
        int off = (wm * 64 + m * 16 + l15) * 72 + s * 32 + l4 * 8;
        ah[m] = *(const bf16x8*)&sm.s.Ah[off];
        al[m] = *(const bf16x8*)&sm.s.Al[off];
      }
#pragma unroll
      for (int n = 0; n < 2; ++n) {
        int off = (wn * 32 + n * 16 + l15) * 72 + s * 32 + l4 * 8;
        bh[n] = *(const bf16x8*)&sm.s.Bh[off];
        bl[n] = *(const bf16x8*)&sm.s.Bl[off];
      }
#pragma unroll
      for (int m = 0; m < 4; ++m)
#pragma unroll
        for (int n = 0; n < 2; ++n) {
          acc[m][n] = __builtin_amdgcn_mfma_f32_16x16x32_bf16(ah[m], bh[n], acc[m][n], 0, 0, 0);
          acc[m][n] = __builtin_amdgcn_mfma_f32_16x16x32_bf16(ah[m], bl[n], acc[m][n], 0, 0, 0);
          acc[m][n] = __builtin_amdgcn_mfma_f32_16x16x32_bf16(al[m], bh[n], acc[m][n], 0, 0, 0);
        }
    }
  };

  stage_issue(va0, vb0, 0);
  for (int kt = 0; kt < NT; kt += 2) {
    const bool has1 = (kt + 1 < NT);
    if (has1) stage_issue(va1, vb1, kt + 1);          // prefetch overlaps compute
    stage_write(va0, vb0, (kt * 64 < K1) ? scaleB1 : 1.0f);
    __syncthreads();
    compute();
    __syncthreads();
    if (has1) {
      if (kt + 2 < NT) stage_issue(va0, vb0, kt + 2);
      stage_write(va1, vb1, ((kt + 1) * 64 < K1) ? scaleB1 : 1.0f);
      __syncthreads();
      compute();
      __syncthreads();
    }
  }

  // Epilogue: z -> LDS (C/D layout: col=lane&15, row=(lane>>4)*4+reg [m89])
#pragma unroll
  for (int m = 0; m < 4; ++m)
#pragma unroll
    for (int n = 0; n < 2; ++n)
#pragma unroll
      for (int j = 0; j < 4; ++j) {
        int row = wm * 64 + m * 16 + l4 * 4 + j;
        int col = wn * 32 + n * 16 + l15;
        sm.z[row * 68 + col] = acc[m][n][j];
      }
  __syncthreads();
#pragma unroll
  for (int i = 0; i < 8; ++i) {
    int idx = i * 256 + tid;
    int b = idx >> 4, hc = idx & 15;
    int jj = hc0 + hc;
    float zi = sm.z[b * 68 + hc]      + bias[jj];
    float zf = sm.z[b * 68 + 16 + hc] + bias[1024 + jj];
    float zg = sm.z[b * 68 + 32 + hc] + bias[2048 + jj];
    float zo = sm.z[b * 68 + 48 + hc] + bias[3072 + jj];
    size_t gi = (size_t)(bm0 + b) * 1024 + jj;
    float cp = cst[gi];
    float si = 1.f / (1.f + expf(-zi));
    float sf = 1.f / (1.f + expf(-zf));
    float so = 1.f / (1.f + expf(-zo));
    float cn = sf * cp + si * tanhf(zg);
    float hn = so * tanhf(cn);
    cst[gi] = cn;
    hout[gi] = hn;
  }
}

// out[row] = dot(h2[row,:], W_out)  for one decoder step
__global__ __launch_bounds__(256, 1) void proj_kernel(
    const float* __restrict__ h2, const float* __restrict__ Wout,
    float* __restrict__ out) {
  int row = blockIdx.x * 4 + (threadIdx.x >> 6);
  int lane = threadIdx.x & 63;
  float s = 0.f;
#pragma unroll
  for (int j = lane; j < 1024; j += 64) s += h2[(size_t)row * 1024 + j] * Wout[j];
#pragma unroll
  for (int off = 32; off; off >>= 1) s += __shfl_down(s, off, 64);
  if (lane == 0) out[row] = s;
}

extern "C" void kernel_launch(void* const* d_in, const int* in_sizes, int n_in,
                              void* d_out, int out_size, void* d_ws, size_t ws_size,
                              hipStream_t stream) {
  (void)in_sizes; (void)n_in; (void)out_size; (void)ws_size;
  const float* x = (const float*)d_in[0];
  // order: ef, d1, d2, df, e1, e2 ; each (Wih, Whh, b)
  const float* Wih[6]; const float* Whh[6]; const float* bb[6];
  for (int i = 0; i < 6; ++i) {
    Wih[i] = (const float*)d_in[1 + 3 * i];
    Whh[i] = (const float*)d_in[2 + 3 * i];
    bb[i]  = (const float*)d_in[3 + 3 * i];
  }
  const float* Wout = (const float*)d_in[19];
  float* out = (float*)d_out;

  const size_t S = (size_t)512 * 1024;
  float* ws = (float*)d_ws;
  float* h0[2] = { ws + 0 * S, ws + 1 * S };
  float* h1[2] = { ws + 2 * S, ws + 3 * S };
  float* h2[2] = { ws + 4 * S, ws + 5 * S };
  float* c0 = ws + 6 * S;
  float* c1 = ws + 7 * S;
  float* c2 = ws + 8 * S;
  float* y  = ws + 9 * S;

  hipMemsetAsync(d_ws, 0, 10 * S * sizeof(float), stream);  // zero h/c state

  dim3 grid(256), block(256);
  int p0 = 0, p1 = 0, p2 = 0;

  // Encoder: ef -> d1 -> d2 per step. x/10000 folded into ef_Wih scale.
  for (int t = 0; t < 168; ++t) {
    lstm_cell<64><<<grid, block, 0, stream>>>(
        x + (size_t)t * 512 * 64, h0[p0], Wih[0], Whh[0], bb[0], c0, h0[p0 ^ 1], 1e-4f);
    p0 ^= 1;
    lstm_cell<1024><<<grid, block, 0, stream>>>(
        h0[p0], h1[p1], Wih[1], Whh[1], bb[1], c1, h1[p1 ^ 1], 1.0f);
    p1 ^= 1;
    lstm_cell<1024><<<grid, block, 0, stream>>>(
        h1[p1], h2[p2], Wih[2], Whh[2], bb[2], c2, h2[p2 ^ 1], 1.0f);
    p2 ^= 1;
  }

  // y = final encoder h2 (h2 keeps evolving in the decoder, so snapshot it)
  hipMemcpyAsync(y, h2[p2], S * sizeof(float), hipMemcpyDeviceToDevice, stream);

  // Decoder: df -> e1 -> e2, project h2 each step
  for (int t = 0; t < 24; ++t) {
    lstm_cell<1024><<<grid, block, 0, stream>>>(
        y, h0[p0], Wih[3], Whh[3], bb[3], c0, h0[p0 ^ 1], 1.0f);
    p0 ^= 1;
    lstm_cell<1024><<<grid, block, 0, stream>>>(
        h0[p0], h1[p1], Wih[4], Whh[4], bb[4], c1, h1[p1 ^ 1], 1.0f);
    p1 ^= 1;
    lstm_cell<1024><<<grid, block, 0, stream>>>(
        h1[p1], h2[p2], Wih[5], Whh[5], bb[5], c2, h2[p2 ^ 1], 1.0f);
    p2 ^= 1;
    proj_kernel<<<dim3(128), block, 0, stream>>>(h2[p2], Wout, out + (size_t)t * 512);
  }
}

// Round 2
// 20579.703 us; speedup vs baseline: 2.2619x; 2.2619x over previous
//
#include <hip/hip_runtime.h>
#include <hip/hip_bf16.h>
#include <cstdint>
#include <cstddef>

// Seq2Seq LSTM: 168 enc + 24 dec steps, 3 layers, B=512, H=1024, IN=64.
// z[512,4096] = [in|h]@W^T + b per cell; fp32 via bf16 hi/lo 3-product MFMA.
// Round 2: weights/x pre-split+pre-swizzled once; cells stage via
// global_load_lds(16B) into XOR-swizzled LDS; depth-2 prefetch, counted vmcnt.

typedef __attribute__((ext_vector_type(8))) short bf16x8;
typedef __attribute__((ext_vector_type(4))) float f32x4;
typedef __attribute__((address_space(3))) char lds_char;
typedef __attribute__((address_space(1))) char glb_char;

__device__ __forceinline__ void split1(float x, ushort &hi, ushort &lo) {
  unsigned u = __float_as_uint(x);
  hi = (ushort)(u >> 16);                         // truncated bf16 (exact)
  float r = x - __uint_as_float(u & 0xffff0000u); // exact remainder
  unsigned v = __float_as_uint(r);
  v += 0x7fffu + ((v >> 16) & 1u);                // RNE to bf16
  lo = (ushort)(v >> 16);
}
__device__ __forceinline__ ushort bf_part(float x, bool lo) {
  ushort h, l; split1(x, h, l); return lo ? l : h;
}

__device__ __forceinline__ void gload16(const char* g, char* l) {
  __builtin_amdgcn_global_load_lds((const __attribute__((address_space(1))) void*)(glb_char*)g,
                                   (__attribute__((address_space(3))) void*)(lds_char*)l,
                                   16, 0, 0);
}

// ---------------- pack kernels (run once per launch, ~trivial cost) --------
// Weight block layout: [hb=64][kt=NT][16KB: 8KB hi | 8KB lo], each half the
// LDS image of a 64x64 bf16 tile with byte swizzle ((r&7)<<4) pre-applied.
__global__ void pack_w_kernel(const float* __restrict__ Wih,
                              const float* __restrict__ Whh,
                              ushort* __restrict__ dst, int K1, int NT,
                              long nchunk) {
  for (long c = blockIdx.x * (long)blockDim.x + threadIdx.x; c < nchunk;
       c += (long)gridDim.x * blockDim.x) {
    long p = c * 8;                       // byte position
    int blk = (int)(p >> 14);
    int off = (int)(p & 16383);
    int hb = blk / NT, kt = blk - hb * NT;
    bool lo = off >= 8192;
    int q = off & 8191;
    int r = q >> 7;
    int k = ((q & 127) ^ ((r & 7) << 4)) >> 1;   // 4 consecutive elems
    int j = (r >> 4) * 1024 + hb * 16 + (r & 15);
    int kcol = kt * 64 + k;
    float4 v;
    if (kcol < K1) v = *(const float4*)(Wih + (size_t)j * K1 + kcol);
    else           v = *(const float4*)(Whh + (size_t)j * 1024 + (kcol - K1));
    ushort4 o;
    o.x = bf_part(v.x, lo); o.y = bf_part(v.y, lo);
    o.z = bf_part(v.z, lo); o.w = bf_part(v.w, lo);
    *(ushort4*)(dst + (p >> 1)) = o;
  }
}

// x block layout: [t=168][mb=4][32KB: 16KB hi | 16KB lo], 128x64 tile image,
// scale 1e-4 folded in.
__global__ void pack_x_kernel(const float* __restrict__ x,
                              ushort* __restrict__ dst, long nchunk) {
  for (long c = blockIdx.x * (long)blockDim.x + threadIdx.x; c < nchunk;
       c += (long)gridDim.x * blockDim.x) {
    long p = c * 8;
    int blk = (int)(p >> 15);            // t*4 + mb
    int off = (int)(p & 32767);
    bool lo = off >= 16384;
    int q = off & 16383;
    int r = q >> 7;
    int k = ((q & 127) ^ ((r & 7) << 4)) >> 1;
    int t = blk >> 2, mb = blk & 3;
    float4 v = *(const float4*)(x + ((size_t)(t * 512 + mb * 128 + r) * 64 + k));
    ushort4 o;
    o.x = bf_part(v.x * 1e-4f, lo); o.y = bf_part(v.y * 1e-4f, lo);
    o.z = bf_part(v.z * 1e-4f, lo); o.w = bf_part(v.w * 1e-4f, lo);
    *(ushort4*)(dst + (p >> 1)) = o;
  }
}

// ---------------- main cell kernel -----------------------------------------
// A1/A2/B are packed pointers. LDS buffer = [Ah 16K|Al 16K|Bh 8K|Bl 8K] = 48K,
// 3 buffers (depth-2 prefetch), counted vmcnt so loads span barriers.
template <int K1>
__global__ __launch_bounds__(256, 1) void lstm_cell(
    const char* __restrict__ A1p, const char* __restrict__ A2p,
    const char* __restrict__ Bp, const float* __restrict__ bias,
    float* __restrict__ cst, char* __restrict__ hpk,
    float* __restrict__ hf) {
  constexpr int NK1 = K1 / 64;
  constexpr int NT = NK1 + 16;
  __shared__ __align__(16) char lds[3 * 49152];

  const int tid = threadIdx.x;
  const int bw = blockIdx.x;
  const int wid = (bw & 7) * 32 + (bw >> 3);   // XCD swizzle
  const int mb = wid & 3, hb = wid >> 2;
  const int bm0 = mb * 128, hc0 = hb * 16;
  const int w = tid >> 6, lane = tid & 63;
  const int wm = w >> 1, wn = w & 1;           // wave 2x2 over 128x64
  const int l15 = lane & 15, l4 = lane >> 4;
  const int laneoff = lane * 16;

  f32x4 acc[4][2];
#pragma unroll
  for (int m = 0; m < 4; ++m)
#pragma unroll
    for (int n = 0; n < 2; ++n) acc[m][n] = (f32x4){0.f, 0.f, 0.f, 0.f};

  auto STAGE = [&](int buf, int kt) {
    const char* asrc;
    if (kt < NK1) asrc = A1p + (((size_t)(mb * NK1 + kt)) << 15);
    else          asrc = A2p + (((size_t)(mb * 16 + (kt - NK1))) << 15);
    const char* bsrc = Bp + (((size_t)(hb * NT + kt)) << 14);
    char* lb = lds + buf * 49152;
#pragma unroll
    for (int i = 0; i < 8; ++i) {
      int o = (i * 4 + w) * 1024;
      gload16(asrc + o + laneoff, lb + o);
    }
#pragma unroll
    for (int i = 0; i < 4; ++i) {
      int o = (i * 4 + w) * 1024;
      gload16(bsrc + o + laneoff, lb + 32768 + o);
    }
  };

  auto COMPUTE = [&](int buf) {
    const char* lb = lds + buf * 49152;
#pragma unroll
    for (int s = 0; s < 2; ++s) {
      bf16x8 ah[4], al[4], bh[2], bl[2];
#pragma unroll
      for (int m = 0; m < 4; ++m) {
        int row = wm * 64 + m * 16 + l15;
        int off = (row * 128 + s * 64 + l4 * 16) ^ ((l15 & 7) << 4);
        ah[m] = *(const bf16x8*)(lb + off);
        al[m] = *(const bf16x8*)(lb + 16384 + off);
      }
#pragma unroll
      for (int n = 0; n < 2; ++n) {
        int row = wn * 32 + n * 16 + l15;
        int off = (row * 128 + s * 64 + l4 * 16) ^ ((l15 & 7) << 4);
        bh[n] = *(const bf16x8*)(lb + 32768 + off);
        bl[n] = *(const bf16x8*)(lb + 40960 + off);
      }
#pragma unroll
      for (int m = 0; m < 4; ++m)
#pragma unroll
        for (int n = 0; n < 2; ++n) {
          acc[m][n] = __builtin_amdgcn_mfma_f32_16x16x32_bf16(ah[m], bh[n], acc[m][n], 0, 0, 0);
          acc[m][n] = __builtin_amdgcn_mfma_f32_16x16x32_bf16(ah[m], bl[n], acc[m][n], 0, 0, 0);
          acc[m][n] = __builtin_amdgcn_mfma_f32_16x16x32_bf16(al[m], bh[n], acc[m][n], 0, 0, 0);
        }
    }
  };

  STAGE(0, 0);
  STAGE(1, 1);
  int cb = 0;  // compute buffer = kt % 3
  for (int kt = 0; kt < NT; ++kt) {
    if (kt + 2 < NT) {
      int sb = cb + 2; if (sb >= 3) sb -= 3;
      STAGE(sb, kt + 2);
      __builtin_amdgcn_sched_barrier(0);
      asm volatile("s_waitcnt vmcnt(24)" ::: "memory");   // tile kt done
    } else if (kt + 1 < NT) {
      __builtin_amdgcn_sched_barrier(0);
      asm volatile("s_waitcnt vmcnt(12)" ::: "memory");
    } else {
      __builtin_amdgcn_sched_barrier(0);
      asm volatile("s_waitcnt vmcnt(0)" ::: "memory");
    }
    __builtin_amdgcn_s_barrier();
    __builtin_amdgcn_sched_barrier(0);
    asm volatile("" ::: "memory");
    COMPUTE(cb);
    __builtin_amdgcn_sched_barrier(0);
    __builtin_amdgcn_s_barrier();   // protect buffer overwrite next iter
    __builtin_amdgcn_sched_barrier(0);
    if (++cb == 3) cb = 0;
  }

  // Epilogue: z -> LDS (C/D layout col=lane&15, row=(lane>>4)*4+reg), gates.
  float* z = (float*)lds;
#pragma unroll
  for (int m = 0; m < 4; ++m)
#pragma unroll
    for (int n = 0; n < 2; ++n)
#pragma unroll
      for (int j = 0; j < 4; ++j) {
        int row = wm * 64 + m * 16 + l4 * 4 + j;
        int col = wn * 32 + n * 16 + l15;
        z[row * 68 + col] = acc[m][n][j];
      }
  __syncthreads();
#pragma unroll
  for (int i = 0; i < 8; ++i) {
    int idx = i * 256 + tid;
    int b = idx >> 4, hc = idx & 15;
    int jj = hc0 + hc;
    float zi = z[b * 68 + hc]      + bias[jj];
    float zf = z[b * 68 + 16 + hc] + bias[1024 + jj];
    float zg = z[b * 68 + 32 + hc] + bias[2048 + jj];
    float zo = z[b * 68 + 48 + hc] + bias[3072 + jj];
    size_t gi = (size_t)(bm0 + b) * 1024 + jj;
    float cp = cst[gi];
    float si = 1.f / (1.f + expf(-zi));
    float sf = 1.f / (1.f + expf(-zf));
    float so = 1.f / (1.f + expf(-zo));
    float cn = sf * cp + si * tanhf(zg);
    float hn = so * tanhf(cn);
    cst[gi] = cn;
    if (hf) hf[gi] = hn;
    // packed hi/lo write in A-tile image layout for downstream cells
    ushort hhi, hlo; split1(hn, hhi, hlo);
    int r = b;                       // row within 128-block
    int kt2 = jj >> 6, k2 = jj & 63;
    size_t blk = ((size_t)(mb * 16 + kt2)) << 15;
    int inner = (k2 * 2) ^ ((r & 7) << 4);
    *(ushort*)(hpk + blk + r * 128 + inner) = hhi;
    *(ushort*)(hpk + blk + 16384 + r * 128 + inner) = hlo;
  }
}

// out[row] = dot(h2[row,:], W_out)
__global__ __launch_bounds__(256, 1) void proj_kernel(
    const float* __restrict__ h2, const float* __restrict__ Wout,
    float* __restrict__ out) {
  int row = blockIdx.x * 4 + (threadIdx.x >> 6);
  int lane = threadIdx.x & 63;
  float s = 0.f;
#pragma unroll
  for (int j = lane; j < 1024; j += 64) s += h2[(size_t)row * 1024 + j] * Wout[j];
#pragma unroll
  for (int off = 32; off; off >>= 1) s += __shfl_down(s, off, 64);
  if (lane == 0) out[row] = s;
}

// ---------------- fallback (round-1 kernel) if ws too small ----------------
struct FbSMemS {
  ushort Ah[128 * 72]; ushort Al[128 * 72];
  ushort Bh[64 * 72];  ushort Bl[64 * 72];
};
union FbSMemU { FbSMemS s; float z[128 * 68]; };

template <int K1>
__global__ __launch_bounds__(256, 1) void lstm_cell_fb(
    const float* __restrict__ A1, const float* __restrict__ A2,
    const float* __restrict__ B1, const float* __restrict__ B2,
    const float* __restrict__ bias, float* __restrict__ cst,
    float* __restrict__ hout, float scaleB1) {
  constexpr int NT = (K1 + 1024) / 64;
  __shared__ FbSMemU sm;
  const int tid = threadIdx.x;
  const int bw = blockIdx.x;
  const int wid = (bw & 7) * 32 + (bw >> 3);
  const int bm0 = (wid & 3) * 128;
  const int hc0 = (wid >> 2) * 16;
  const int frow = tid >> 4;
  const int fcol = (tid & 15) << 2;
  const int w = tid >> 6, lane = tid & 63;
  const int wm = w >> 1, wn = w & 1;
  const int l15 = lane & 15, l4 = lane >> 4;

  f32x4 acc[4][2];
#pragma unroll
  for (int m = 0; m < 4; ++m)
#pragma unroll
    for (int n = 0; n < 2; ++n) acc[m][n] = (f32x4){0.f, 0.f, 0.f, 0.f};

  float4 va0[8], vb0[4], va1[8], vb1[4];
  auto stage_issue = [&](float4(&va)[8], float4(&vb)[4], int kt) {
    const int k0 = kt * 64;
    const float* sA; int ldA, ka;
    if (k0 < K1) { sA = A1; ldA = K1; ka = k0; }
    else         { sA = A2; ldA = 1024; ka = k0 - K1; }
#pragma unroll
    for (int i = 0; i < 8; ++i)
      va[i] = *(const float4*)(sA + (size_t)(bm0 + frow + 16 * i) * ldA + ka + fcol);
    const float* sB; int ldB, kb;
    if (k0 < K1) { sB = B1; ldB = K1; kb = k0; }
    else         { sB = B2; ldB = 1024; kb = k0 - K1; }
#pragma unroll
    for (int i = 0; i < 4; ++i)
      vb[i] = *(const float4*)(sB + (size_t)(i * 1024 + hc0 + frow) * ldB + kb + fcol);
  };
  auto stage_write = [&](float4(&va)[8], float4(&vb)[4], float scB) {
#pragma unroll
    for (int i = 0; i < 8; ++i) {
      ushort h0, h1, h2, h3, l0, l1, l2, l3;
      split1(va[i].x, h0, l0); split1(va[i].y, h1, l1);
      split1(va[i].z, h2, l2); split1(va[i].w, h3, l3);
      *(ushort4*)&sm.s.Ah[(frow + 16 * i) * 72 + fcol] = make_ushort4(h0, h1, h2, h3);
      *(ushort4*)&sm.s.Al[(frow + 16 * i) * 72 + fcol] = make_ushort4(l0, l1, l2, l3);
    }
#pragma unroll
    for (int i = 0; i < 4; ++i) {
      ushort h0, h1, h2, h3, l0, l1, l2, l3;
      split1(vb[i].x * scB, h0, l0); split1(vb[i].y * scB, h1, l1);
      split1(vb[i].z * scB, h2, l2); split1(vb[i].w * scB, h3, l3);
      *(ushort4*)&sm.s.Bh[(frow + 16 * i) * 72 + fcol] = make_ushort4(h0, h1, h2, h3);
      *(ushort4*)&sm.s.Bl[(frow + 16 * i) * 72 + fcol] = make_ushort4(l0, l1, l2, l3);
    }
  };
  auto compute = [&]() {
#pragma unroll
    for (int s = 0; s < 2; ++s) {
      bf16x8 ah[4], al[4], bh[2], bl[2];
#pragma unroll
      for (int m = 0; m < 4; ++m) {
        int off = (wm * 64 + m * 16 + l15) * 72 + s * 32 + l4 * 8;
        ah[m] = *(const bf16x8*)&sm.s.Ah[off];
        al[m] = *(const bf16x8*)&sm.s.Al[off];
      }
#pragma unroll
      for (int n = 0; n < 2; ++n) {
        int off = (wn * 32 + n * 16 + l15) * 72 + s * 32 + l4 * 8;
        bh[n] = *(const bf16x8*)&sm.s.Bh[off];
        bl[n] = *(const bf16x8*)&sm.s.Bl[off];
      }
#pragma unroll
      for (int m = 0; m < 4; ++m)
#pragma unroll
        for (int n = 0; n < 2; ++n) {
          acc[m][n] = __builtin_amdgcn_mfma_f32_16x16x32_bf16(ah[m], bh[n], acc[m][n], 0, 0, 0);
          acc[m][n] = __builtin_amdgcn_mfma_f32_16x16x32_bf16(ah[m], bl[n], acc[m][n], 0, 0, 0);
          acc[m][n] = __builtin_amdgcn_mfma_f32_16x16x32_bf16(al[m], bh[n], acc[m][n], 0, 0, 0);
        }
    }
  };

  stage_issue(va0, vb0, 0);
  for (int kt = 0; kt < NT; kt += 2) {
    const bool has1 = (kt + 1 < NT);
    if (has1) stage_issue(va1, vb1, kt + 1);
    stage_write(va0, vb0, (kt * 64 < K1) ? scaleB1 : 1.0f);
    __syncthreads();
    compute();
    __syncthreads();
    if (has1) {
      if (kt + 2 < NT) stage_issue(va0, vb0, kt + 2);
      stage_write(va1, vb1, ((kt + 1) * 64 < K1) ? scaleB1 : 1.0f);
      __syncthreads();
      compute();
      __syncthreads();
    }
  }
#pragma unroll
  for (int m = 0; m < 4; ++m)
#pragma unroll
    for (int n = 0; n < 2; ++n)
#pragma unroll
      for (int j = 0; j < 4; ++j) {
        int row = wm * 64 + m * 16 + l4 * 4 + j;
        int col = wn * 32 + n * 16 + l15;
        sm.z[row * 68 + col] = acc[m][n][j];
      }
  __syncthreads();
#pragma unroll
  for (int i = 0; i < 8; ++i) {
    int idx = i * 256 + tid;
    int b = idx >> 4, hc = idx & 15;
    int jj = hc0 + hc;
    float zi = sm.z[b * 68 + hc]      + bias[jj];
    float zf = sm.z[b * 68 + 16 + hc] + bias[1024 + jj];
    float zg = sm.z[b * 68 + 32 + hc] + bias[2048 + jj];
    float zo = sm.z[b * 68 + 48 + hc] + bias[3072 + jj];
    size_t gi = (size_t)(bm0 + b) * 1024 + jj;
    float cp = cst[gi];
    float si = 1.f / (1.f + expf(-zi));
    float sf = 1.f / (1.f + expf(-zf));
    float so = 1.f / (1.f + expf(-zo));
    float cn = sf * cp + si * tanhf(zg);
    float hn = so * tanhf(cn);
    cst[gi] = cn;
    hout[gi] = hn;
  }
}

extern "C" void kernel_launch(void* const* d_in, const int* in_sizes, int n_in,
                              void* d_out, int out_size, void* d_ws, size_t ws_size,
                              hipStream_t stream) {
  (void)in_sizes; (void)n_in; (void)out_size;
  const float* x = (const float*)d_in[0];
  const float* Wih[6]; const float* Whh[6]; const float* bb[6];
  for (int i = 0; i < 6; ++i) {
    Wih[i] = (const float*)d_in[1 + 3 * i];
    Whh[i] = (const float*)d_in[2 + 3 * i];
    bb[i]  = (const float*)d_in[3 + 3 * i];
  }
  const float* Wout = (const float*)d_in[19];
  float* out = (float*)d_out;

  const size_t NEED = 230686720;
  if (ws_size >= NEED) {
    // ---- fast path: packed weights ----
    char* W = (char*)d_ws;
    const size_t MB2 = 2097152;
    float* c0 = (float*)(W + 0 * MB2);
    float* c1 = (float*)(W + 1 * MB2);
    float* c2 = (float*)(W + 2 * MB2);
    char* h0p[2] = { W + 3 * MB2, W + 4 * MB2 };
    char* h1p[2] = { W + 5 * MB2, W + 6 * MB2 };
    char* h2p[2] = { W + 7 * MB2, W + 8 * MB2 };
    char* yp = W + 9 * MB2;
    float* hf = (float*)(W + 10 * MB2);
    char* xp = W + 11 * MB2;
    char* wp[6];
    wp[0] = xp + 22020096;
    wp[1] = wp[0] + 17825792;
    for (int i = 2; i < 6; ++i) wp[i] = wp[i - 1] + 33554432;

    hipMemsetAsync(W, 0, 9 * MB2, stream);  // c + all packed-h state

    pack_w_kernel<<<dim3(1024), dim3(256), 0, stream>>>(
        Wih[0], Whh[0], (ushort*)wp[0], 64, 17, 64L * 17 * 2048);
    for (int i = 1; i < 6; ++i)
      pack_w_kernel<<<dim3(1024), dim3(256), 0, stream>>>(
          Wih[i], Whh[i], (ushort*)wp[i], 1024, 32, 64L * 32 * 2048);
    pack_x_kernel<<<dim3(1024), dim3(256), 0, stream>>>(
        x, (ushort*)xp, 22020096L / 8);

    dim3 grid(256), block(256);
    int p0 = 0, p1 = 0, p2 = 0;
    for (int t = 0; t < 168; ++t) {
      lstm_cell<64><<<grid, block, 0, stream>>>(
          xp + (size_t)t * 131072, h0p[p0], wp[0], bb[0], c0, h0p[p0 ^ 1], nullptr);
      p0 ^= 1;
      lstm_cell<1024><<<grid, block, 0, stream>>>(
          h0p[p0], h1p[p1], wp[1], bb[1], c1, h1p[p1 ^ 1], nullptr);
      p1 ^= 1;
      lstm_cell<1024><<<grid, block, 0, stream>>>(
          h1p[p1], h2p[p2], wp[2], bb[2], c2, h2p[p2 ^ 1], nullptr);
      p2 ^= 1;
    }
    hipMemcpyAsync(yp, h2p[p2], MB2, hipMemcpyDeviceToDevice, stream);
    for (int t = 0; t < 24; ++t) {
      lstm_cell<1024><<<grid, block, 0, stream>>>(
          yp, h0p[p0], wp[3], bb[3], c0, h0p[p0 ^ 1], nullptr);
      p0 ^= 1;
      lstm_cell<1024><<<grid, block, 0, stream>>>(
          h0p[p0], h1p[p1], wp[4], bb[4], c1, h1p[p1 ^ 1], nullptr);
      p1 ^= 1;
      lstm_cell<1024><<<grid, block, 0, stream>>>(
          h1p[p1], h2p[p2], wp[5], bb[5], c2, h2p[p2 ^ 1], hf);
      p2 ^= 1;
      proj_kernel<<<dim3(128), block, 0, stream>>>(hf, Wout, out + (size_t)t * 512);
    }
  } else {
    // ---- fallback: round-1 path (fp32 in ws, on-the-fly split) ----
    const size_t S = (size_t)512 * 1024;
    float* ws = (float*)d_ws;
    float* h0[2] = { ws + 0 * S, ws + 1 * S };
    float* h1[2] = { ws + 2 * S, ws + 3 * S };
    float* h2[2] = { ws + 4 * S, ws + 5 * S };
    float* c0 = ws + 6 * S;
    float* c1 = ws + 7 * S;
    float* c2 = ws + 8 * S;
    float* y  = ws + 9 * S;
    hipMemsetAsync(d_ws, 0, 10 * S * sizeof(float), stream);
    dim3 grid(256), block(256);
    int p0 = 0, p1 = 0, p2 = 0;
    for (int t = 0; t < 168; ++t) {
      lstm_cell_fb<64><<<grid, block, 0, stream>>>(
          x + (size_t)t * 512 * 64, h0[p0], Wih[0], Whh[0], bb[0], c0, h0[p0 ^ 1], 1e-4f);
      p0 ^= 1;
      lstm_cell_fb<1024><<<grid, block, 0, stream>>>(
          h0[p0], h1[p1], Wih[1], Whh[1], bb[1], c1, h1[p1 ^ 1], 1.0f);
      p1 ^= 1;
      lstm_cell_fb<1024><<<grid, block, 0, stream>>>(
          h1[p1], h2[p2], Wih[2], Whh[2], bb[2], c2, h2[p2 ^ 1], 1.0f);
      p2 ^= 1;
    }
    hipMemcpyAsync(y, h2[p2], S * sizeof(float), hipMemcpyDeviceToDevice, stream);
    for (int t = 0; t < 24; ++t) {
      lstm_cell_fb<1024><<<grid, block, 0, stream>>>(
          y, h0[p0], Wih[3], Whh[3], bb[3], c0, h0[p0 ^ 1], 1.0f);
      p0 ^= 1;
      lstm_cell_fb<1024><<<grid, block, 0, stream>>>(
          h0[p0], h1[p1], Wih[4], Whh[4], bb[4], c1, h1[p1 ^ 1], 1.0f);
      p1 ^= 1;
      lstm_cell_fb<1024><<<grid, block, 0, stream>>>(
          h1[p1], h2[p2], Wih[5], Whh[5], bb[5], c2, h2[p2 ^ 1], 1.0f);
      p2 ^= 1;
      proj_kernel<<<dim3(128), block, 0, stream>>>(h2[p2], Wout, out + (size_t)t * 512);
    }
  }
}